// Round 2
// baseline (481.831 us; speedup 1.0000x reference)
//
#include <hip/hip_runtime.h>
#include <cstdint>
#include <math.h>

typedef float f32x4 __attribute__((ext_vector_type(4)));

// Skinny GEMM: Y[row][k] = sum_j A[row][j] * MT[k][j]   (MT is K x nj, transposed operand)
// Block: 256 threads = 4 waves; wave owns 4 rows (block = 16 rows); lanes stride j by float4.
// NO LDS, NO barriers: MT is small (<=512 KB) and L1/L2-hot, read directly per lane.
// A streamed with nontemporal loads + 2-tile register prefetch (a0/a1), so the only
// waits are fine-grained vmcnt on in-flight loads — waves pipeline freely.
// EPI 0: store Y transposed to out[K][ldo]
// EPI 1: h=relu(Y+bias); out[k2][row] = sum_k h[k]*W2[k][k2]
// EPI 2: out[row*8+k] = relu(Y+bias)
template<int K, int EPI>
__launch_bounds__(256, 2)
__global__ void skinny_gemm(const float* __restrict__ A, int lda, int nj,
                            const float* __restrict__ MT, int ldm,
                            float* __restrict__ out, int ldo,
                            const float* __restrict__ bias,
                            const float* __restrict__ W2)
{
    const int lane = (int)(threadIdx.x & 63);
    const int wave = (int)(threadIdx.x >> 6);
    const int row0 = blockIdx.x * 16 + wave * 4;

    float acc[4][K];
#pragma unroll
    for (int r = 0; r < 4; ++r)
#pragma unroll
        for (int k = 0; k < K; ++k) acc[r][k] = 0.f;

    const int ntiles = nj / 256;

    const float* ap[4];
#pragma unroll
    for (int r = 0; r < 4; ++r)
        ap[r] = A + (size_t)(row0 + r) * lda + lane * 4;
    const float* mp = MT + lane * 4;

    // 2-deep A prefetch in registers
    f32x4 a0[4], a1[4];
#pragma unroll
    for (int r = 0; r < 4; ++r)
        a0[r] = __builtin_nontemporal_load((const f32x4*)(ap[r]));
    if (ntiles > 1) {
#pragma unroll
        for (int r = 0; r < 4; ++r)
            a1[r] = __builtin_nontemporal_load((const f32x4*)(ap[r] + 256));
    }

    for (int t = 0; t < ntiles; t += 2) {
        {   // tile t: consume a0, then prefetch t+2 into a0
            const float* mt = mp + (size_t)t * 256;
#pragma unroll
            for (int k = 0; k < K; ++k) {
                const f32x4 m = *(const f32x4*)(mt + (size_t)k * ldm);
#pragma unroll
                for (int r = 0; r < 4; ++r)
                    acc[r][k] += a0[r].x * m.x + a0[r].y * m.y
                               + a0[r].z * m.z + a0[r].w * m.w;
            }
            if (t + 2 < ntiles) {
#pragma unroll
                for (int r = 0; r < 4; ++r)
                    a0[r] = __builtin_nontemporal_load((const f32x4*)(ap[r] + (size_t)(t + 2) * 256));
            }
        }
        if (t + 1 < ntiles) {   // tile t+1: consume a1, prefetch t+3 into a1
            const float* mt = mp + (size_t)(t + 1) * 256;
#pragma unroll
            for (int k = 0; k < K; ++k) {
                const f32x4 m = *(const f32x4*)(mt + (size_t)k * ldm);
#pragma unroll
                for (int r = 0; r < 4; ++r)
                    acc[r][k] += a1[r].x * m.x + a1[r].y * m.y
                               + a1[r].z * m.z + a1[r].w * m.w;
            }
            if (t + 3 < ntiles) {
#pragma unroll
                for (int r = 0; r < 4; ++r)
                    a1[r] = __builtin_nontemporal_load((const f32x4*)(ap[r] + (size_t)(t + 3) * 256));
            }
        }
    }

    // butterfly reduce over 64 lanes: every lane ends with the full sums
#pragma unroll
    for (int s = 1; s < 64; s <<= 1)
#pragma unroll
        for (int r = 0; r < 4; ++r)
#pragma unroll
            for (int k = 0; k < K; ++k)
                acc[r][k] += __shfl_xor(acc[r][k], s, 64);

    if (EPI == 0) {
        if (lane < K) {
#pragma unroll
            for (int r = 0; r < 4; ++r) {
                float v = acc[r][0];
#pragma unroll
                for (int k = 1; k < K; ++k) if (lane == k) v = acc[r][k];
                out[(size_t)lane * ldo + row0 + r] = v;
            }
        }
    } else if (EPI == 1) {
        if (lane < 8) {
#pragma unroll
            for (int r = 0; r < 4; ++r) {
                float p = 0.f;
#pragma unroll
                for (int k = 0; k < K; ++k) {
                    float h = acc[r][k] + bias[k];
                    h = h > 0.f ? h : 0.f;
                    p += h * W2[k * 8 + lane];
                }
                out[(size_t)lane * ldo + row0 + r] = p;
            }
        }
    } else { // EPI == 2
        if (lane < 8) {
#pragma unroll
            for (int r = 0; r < 4; ++r) {
                float v = acc[r][0];
#pragma unroll
                for (int k = 1; k < K; ++k) if (lane == k) v = acc[r][k];
                v += bias[lane];
                v = v > 0.f ? v : 0.f;
                out[(size_t)(row0 + r) * 8 + lane] = v;
            }
        }
    }
}

__global__ void transpose_w1(const float* __restrict__ W1, float* __restrict__ W1T)
{
    const int i = blockIdx.x * 256 + threadIdx.x;   // 4096 elements
    const int k = i >> 8, c = i & 255;
    W1T[i] = W1[c * 16 + k];
}

__global__ void tree_epilogue(const float* __restrict__ z,      // [N][8] row-major
                              const float* __restrict__ Wd,     // [8][16]
                              const float* __restrict__ bd,     // [16]
                              const float* __restrict__ mask,   // [16][16]
                              const float* __restrict__ Wdec,   // [16][16]
                              const float* __restrict__ bdec,   // [16]
                              const float* __restrict__ pi,     // [16][10]
                              float* __restrict__ out)          // [N][10]
{
    const int row = blockIdx.x * blockDim.x + threadIdx.x;
    float zv[8];
#pragma unroll
    for (int k = 0; k < 8; ++k) zv[k] = z[(size_t)row * 8 + k];

    float feat[16];
#pragma unroll
    for (int f = 0; f < 16; ++f) {
        float s = bd[f];
#pragma unroll
        for (int k = 0; k < 8; ++k) s += zv[k] * Wd[k * 16 + f];
        feat[f] = s > 0.f ? s : 0.f;
    }
    float fm[16];
#pragma unroll
    for (int f = 0; f < 16; ++f) {
        float s = 0.f;
#pragma unroll
        for (int g = 0; g < 16; ++g) s += feat[g] * mask[g * 16 + f];
        fm[f] = s;
    }
    float mu[16];
#pragma unroll
    for (int j = 0; j < 8; ++j) {
        const int f = 8 + j;
        float s = bdec[f];
#pragma unroll
        for (int g = 0; g < 16; ++g) s += fm[g] * Wdec[g * 16 + f];
        const float d = 1.f / (1.f + expf(-s));
        mu[2 * j]     = fm[f] * d;
        mu[2 * j + 1] = fm[f] * (1.f - d);
    }
#pragma unroll
    for (int c = 0; c < 10; ++c) {
        float s = 0.f;
#pragma unroll
        for (int m = 0; m < 16; ++m) {
            float p = pi[m * 10 + c];
            p = p > 0.f ? p : 0.f;
            s += mu[m] * p;
        }
        out[(size_t)row * 10 + c] = s;
    }
}

extern "C" void kernel_launch(void* const* d_in, const int* in_sizes, int n_in,
                              void* d_out, int out_size, void* d_ws, size_t ws_size,
                              hipStream_t stream)
{
    const float* X    = (const float*)d_in[0];   // [8192][256]
    const float* A    = (const float*)d_in[1];   // [8192][8192]
    const float* W1   = (const float*)d_in[2];   // [256][16]
    const float* b1   = (const float*)d_in[3];   // [16]
    const float* W2   = (const float*)d_in[4];   // [16][8]
    const float* b2   = (const float*)d_in[5];   // [8]
    const float* Wd   = (const float*)d_in[6];   // [8][16]
    const float* bd   = (const float*)d_in[7];   // [16]
    const float* mask = (const float*)d_in[8];   // [16][16]
    const float* Wdec = (const float*)d_in[9];   // [16][16]
    const float* bdec = (const float*)d_in[10];  // [16]
    const float* pi   = (const float*)d_in[11];  // [16][10]
    float* out = (float*)d_out;

    char* ws = (char*)d_ws;
    float* W1T = (float*)ws;                                  // 16*256*4   = 16 KB
    float* M1T = (float*)(ws + 16 * 1024);                    // 16*8192*4  = 512 KB
    float* PT  = (float*)(ws + 16 * 1024 + 512 * 1024);       // 8*8192*4   = 256 KB
    float* z   = (float*)(ws + 16 * 1024 + 768 * 1024);       // 8192*8*4   = 256 KB

    const int N = 8192;

    // W1T[k][c] = W1[c][k]
    hipLaunchKernelGGL(transpose_w1, dim3(16), dim3(256), 0, stream, W1, W1T);
    // M1T = (X @ W1)^T                      [16][8192]
    hipLaunchKernelGGL((skinny_gemm<16, 0>), dim3(N / 16), dim3(256), 0, stream,
                       X, 256, 256, W1T, 256, M1T, N, (const float*)nullptr, (const float*)nullptr);
    // PT = (relu(A @ M1 + b1) @ W2)^T       [8][8192]
    hipLaunchKernelGGL((skinny_gemm<16, 1>), dim3(N / 16), dim3(256), 0, stream,
                       A, N, N, M1T, N, PT, N, b1, W2);
    // z = relu(A @ P + b2)                  [8192][8] row-major
    hipLaunchKernelGGL((skinny_gemm<8, 2>), dim3(N / 16), dim3(256), 0, stream,
                       A, N, N, PT, N, z, 8, b2, (const float*)nullptr);
    // tree + pi
    hipLaunchKernelGGL(tree_epilogue, dim3(N / 256), dim3(256), 0, stream,
                       z, Wd, bd, mask, Wdec, bdec, pi, out);
}